// Round 3
// baseline (180.558 us; speedup 1.0000x reference)
//
#include <hip/hip_runtime.h>
#include <math.h>

#define Himg 128
#define Wimg 128
#define HW   16384      // 128*128
#define Cin  64
#define Kk   9
#define OUTC 128
#define Bsz  8

typedef __attribute__((ext_vector_type(8))) _Float16 half8;
typedef __attribute__((ext_vector_type(4))) float   floatx4;

#define SPL8(v) ((half8){(v),(v),(v),(v),(v),(v),(v),(v)})

// ---------------------------------------------------------------------------
// fused prep kernel:
//   blocks    0..1023 : transpose+convert x[b][c][h][w] f32 -> xt[b][h][w][c] f16
//   blocks 1024..1311 : repack w_conv into MFMA-fragment order (wpk_h)
//   blocks 1312..1383 : repack w_offset/w_mask into fragment order (wpk2)
// ---------------------------------------------------------------------------
__global__ __launch_bounds__(256) void prep(const float* __restrict__ x,
                                            const float* __restrict__ w_conv,
                                            const float* __restrict__ w_offset,
                                            const float* __restrict__ w_mask,
                                            _Float16* __restrict__ xt,
                                            _Float16* __restrict__ wpk_h,
                                            _Float16* __restrict__ wpk2) {
    __shared__ _Float16 tile[Cin][130];
    int t   = threadIdx.x;
    int bid = blockIdx.x;

    if (bid < 1024) {                       // ---- transpose ----
        int b = bid >> 7;
        int h = bid & 127;
        const float* xb = x + (size_t)b * Cin * HW + (size_t)h * Wimg;
#pragma unroll
        for (int j = 0; j < 32; ++j) {
            int e = t + j * 256;            // 0..8191
            int c = e >> 7;
            int w = e & 127;
            tile[c][w] = (_Float16)xb[(size_t)c * HW + w];
        }
        __syncthreads();
        unsigned* dst = (unsigned*)xt + ((size_t)b * HW + (size_t)h * Wimg) * 32;
#pragma unroll
        for (int j = 0; j < 16; ++j) {
            int d  = t + j * 256;           // 0..4095
            int w  = d >> 5;
            int cp = d & 31;
            union { unsigned u; _Float16 hh[2]; } pk;
            pk.hh[0] = tile[2 * cp][w];
            pk.hh[1] = tile[2 * cp + 1][w];
            dst[d] = pk.u;
        }
        return;
    }

    if (bid < 1024 + 288) {                 // ---- repack main conv weights ----
        int idx = (bid - 1024) * 256 + t;   // 0 .. 73727
        if (idx < Kk * Cin * OUTC) {
            int i    = idx & 7;
            int l    = (idx >> 3) & 63;
            int g    = idx >> 9;            // 0..143
            int mt   = g & 7;
            int ch   = g >> 3;              // 0..17
            int kq   = l >> 4;
            int ln16 = l & 15;
            int o    = mt * 16 + ln16;
            int kl   = kq * 8 + i;
            int c    = (ch & 1) * 32 + kl;
            int kt   = ch >> 1;
            wpk_h[idx] = (_Float16)w_conv[(o * Cin + c) * 9 + kt];
        }
        return;
    }

    {                                       // ---- repack offset/mask weights ----
        int idx = (bid - 1312) * 256 + t;   // 0 .. 18431
        if (idx < 18 * 32 * 32) {
            int i    = idx & 7;
            int l    = (idx >> 3) & 63;
            int g    = idx >> 9;            // 0..35
            int mt0  = g & 1;
            int ch   = g >> 1;              // 0..17
            int kq   = l >> 4;
            int ln16 = l & 15;
            int m    = mt0 * 16 + ln16;
            int kl   = kq * 8 + i;
            int c    = (ch & 1) * 32 + kl;
            int kt   = ch >> 1;
            float v = 0.0f;
            if (m < 18)      v = w_offset[(m * Cin + c) * 9 + kt];
            else if (m < 27) v = w_mask[((m - 18) * Cin + c) * 9 + kt];
            wpk2[idx] = (_Float16)v;
        }
    }
}

// ---------------------------------------------------------------------------
// Fused kernel. Lane mapping for all x-side memory: q = t>>2 (pixel),
// c4 = t&3 (16B channel-quarter). Weights: direct global->VGPR fragment loads.
// Gathers: 2-deep register pipeline in EXPLICITLY NAMED registers (macros,
// compile-time indices only -- no address-taken arrays, no scratch).
// Combine: packed-f16 (v_pk_fma_f16).
// ---------------------------------------------------------------------------
__global__ __launch_bounds__(256, 4) void deform_fused(
        const _Float16* __restrict__ xt, const _Float16* __restrict__ wpk_h,
        const _Float16* __restrict__ wpk2,
        const float* __restrict__ b_offset, const float* __restrict__ b_mask,
        float* __restrict__ out) {
    __shared__ union SMem {
        struct { _Float16 V0[2][64][40]; float P[32][66]; } p0;  // 18688 B
        struct { _Float16 V[2][64][40]; } p1;                    // 10240 B
    } sm;

    int t    = threadIdx.x;
    int bid  = blockIdx.x;
    int b    = bid & 7;                      // XCD-batch swizzle
    int pb   = bid >> 3;                     // 0..255
    int pix0 = pb * 64;
    int h    = pix0 >> 7;
    int w0   = pix0 & 127;                   // 0 or 64

    int lane = t & 63;
    int wv   = t >> 6;
    int q    = t >> 2;                       // pixel 0..63 (block-wide)
    int c4   = t & 3;                        // channel quarter (16B) in 32-ch half
    int kq   = lane >> 4;
    int ln16 = lane & 15;

    const _Float16* xtb  = xt + (size_t)b * HW * Cin;
    const half8* wsrc    = (const half8*)wpk_h;
    const half8* w2src   = (const half8*)wpk2;

    // ================= phase 0: offset/mask conv =================
    floatx4 acc2[2];
    acc2[0] = (floatx4){0.f, 0.f, 0.f, 0.f};
    acc2[1] = (floatx4){0.f, 0.f, 0.f, 0.f};
    int mt0 = wv & 1;                        // wave's m-tile
    int ntA = wv >> 1;                       // wave's n-tiles: ntA, ntA+2

    half8 pvA, pvB, af;

#define LOADX0(chn, DST) { \
    const int ktn = (chn) >> 1, cgn = (chn) & 1; \
    int row = h + (ktn / 3) - 1; \
    int col = w0 + q + (ktn % 3) - 1; \
    bool okc = (row >= 0) && (row < Himg) && (col >= 0) && (col < Wimg); \
    if (okc) DST = *(const half8*)(xtb + ((size_t)(row * Wimg + col)) * Cin \
                                   + cgn * 32 + c4 * 8); \
    else     DST = SPL8((_Float16)0.0f); \
}

#define P0STEP(ch, PV) { \
    *(half8*)&sm.p0.V0[(ch) & 1][q][c4 * 8] = PV; \
    half8 afc = af; \
    if ((ch) < 16) LOADX0((ch) + 2, PV); \
    if ((ch) < 17) af = w2src[((size_t)((ch) + 1) * 2 + mt0) * 64 + lane]; \
    __syncthreads(); \
    half8 b0 = *(const half8*)&sm.p0.V0[(ch) & 1][ntA * 16 + ln16][kq * 8]; \
    half8 b1 = *(const half8*)&sm.p0.V0[(ch) & 1][(ntA + 2) * 16 + ln16][kq * 8]; \
    acc2[0] = __builtin_amdgcn_mfma_f32_16x16x32_f16(afc, b0, acc2[0], 0, 0, 0); \
    acc2[1] = __builtin_amdgcn_mfma_f32_16x16x32_f16(afc, b1, acc2[1], 0, 0, 0); \
}

    LOADX0(0, pvA)
    LOADX0(1, pvB)
    af = w2src[(size_t)mt0 * 64 + lane];

    P0STEP(0,  pvA) P0STEP(1,  pvB) P0STEP(2,  pvA) P0STEP(3,  pvB)
    P0STEP(4,  pvA) P0STEP(5,  pvB) P0STEP(6,  pvA) P0STEP(7,  pvB)
    P0STEP(8,  pvA) P0STEP(9,  pvB) P0STEP(10, pvA) P0STEP(11, pvB)
    P0STEP(12, pvA) P0STEP(13, pvB) P0STEP(14, pvA) P0STEP(15, pvB)
    P0STEP(16, pvA) P0STEP(17, pvB)

    // write P (27 used rows x 64 px, fp32) — P disjoint from V0, no race
#pragma unroll
    for (int j = 0; j < 2; ++j) {
        int nt = ntA + 2 * j;
#pragma unroll
        for (int r = 0; r < 4; ++r)
            sm.p0.P[mt0 * 16 + kq * 4 + r][nt * 16 + ln16] = acc2[j][r];
    }
    __syncthreads();

    // ---- per-pixel geometry (pixel q) -> registers ----
    // geomr[k] = o00 | dx1<<14 | dy1<<15  (cell index + corner-step flags)
    int      geomr[9];
    unsigned wab[9], wcd[9];                 // f16-packed (w00,w01),(w10,w11)
    {
        float fh = (float)h, fw = (float)(w0 + q);
#pragma unroll
        for (int k = 0; k < 9; ++k) {
            float dyv = sm.p0.P[2 * k][q]     + b_offset[2 * k];
            float dxv = sm.p0.P[2 * k + 1][q] + b_offset[2 * k + 1];
            float mz  = sm.p0.P[18 + k][q]    + b_mask[k];
            float mkv = 1.0f / (1.0f + expf(-mz));

            float gy  = fh + (float)(k / 3) - 1.0f + dyv;
            float gx  = fw + (float)(k % 3) - 1.0f + dxv;
            float y0f = floorf(gy), x0f = floorf(gx);
            int   y0  = (int)y0f,   x0 = (int)x0f;
            float wy  = gy - y0f,   wx = gx - x0f;
            int   y1  = y0 + 1,     x1 = x0 + 1;

            bool vy0 = (y0 >= 0) && (y0 < Himg);
            bool vy1 = (y1 >= 0) && (y1 < Himg);
            bool vx0 = (x0 >= 0) && (x0 < Wimg);
            bool vx1 = (x1 >= 0) && (x1 < Wimg);

            float w00 = (vy0 && vx0) ? (1.0f - wy) * (1.0f - wx) * mkv : 0.0f;
            float w01 = (vy0 && vx1) ? (1.0f - wy) * wx          * mkv : 0.0f;
            float w10 = (vy1 && vx0) ? wy          * (1.0f - wx) * mkv : 0.0f;
            float w11 = (vy1 && vx1) ? wy          * wx          * mkv : 0.0f;

            int y0c = min(max(y0, 0), Himg - 1), y1c = min(max(y1, 0), Himg - 1);
            int x0c = min(max(x0, 0), Wimg - 1), x1c = min(max(x1, 0), Wimg - 1);
            geomr[k] = (y0c * Wimg + x0c) | ((x1c - x0c) << 14) | ((y1c - y0c) << 15);
            union { unsigned u; _Float16 hh[2]; } pk;
            pk.hh[0] = (_Float16)w00; pk.hh[1] = (_Float16)w01; wab[k] = pk.u;
            pk.hh[0] = (_Float16)w10; pk.hh[1] = (_Float16)w11; wcd[k] = pk.u;
        }
    }

    // ================= phase 1: deformable sampling + GEMM =================
    floatx4 acc[2][4];
#pragma unroll
    for (int i = 0; i < 2; ++i)
#pragma unroll
        for (int j = 0; j < 4; ++j) acc[i][j] = (floatx4){0.f, 0.f, 0.f, 0.f};
    int m0 = wv * 32;

    half8 gA0, gA1, gA2, gA3, gB0, gB1, gB2, gB3, ar0, ar1;

#define LOADG(chn, D0, D1, D2, D3) { \
    int gg = geomr[(chn) >> 1]; \
    const _Float16* xc = xtb + (size_t)(gg & 0x3fff) * Cin \
                         + ((chn) & 1) * 32 + c4 * 8; \
    int ob = (gg & 0x4000) >> 8;   /* dx1*64   */ \
    int oc = (gg & 0x8000) >> 2;   /* dy1*8192 */ \
    D0 = *(const half8*)(xc); \
    D1 = *(const half8*)(xc + ob); \
    D2 = *(const half8*)(xc + oc); \
    D3 = *(const half8*)(xc + oc + ob); \
}

#define P1STEP(ch, G0, G1, G2, G3) { \
    union { unsigned u; _Float16 hh[2]; } u1, u2; \
    u1.u = wab[(ch) >> 1];  u2.u = wcd[(ch) >> 1]; \
    half8 vv = G0 * SPL8(u1.hh[0]) + G1 * SPL8(u1.hh[1]) \
             + G2 * SPL8(u2.hh[0]) + G3 * SPL8(u2.hh[1]); \
    *(half8*)&sm.p1.V[(ch) & 1][q][c4 * 8] = vv; \
    half8 a0c = ar0, a1c = ar1; \
    if ((ch) < 16) LOADG((ch) + 2, G0, G1, G2, G3); \
    if ((ch) < 17) { \
        ar0 = wsrc[((size_t)((ch) + 1) * 8 + 2 * wv) * 64 + lane]; \
        ar1 = wsrc[((size_t)((ch) + 1) * 8 + 2 * wv + 1) * 64 + lane]; \
    } \
    __syncthreads(); \
    half8 bf0 = *(const half8*)&sm.p1.V[(ch) & 1][ 0 + ln16][kq * 8]; \
    half8 bf1 = *(const half8*)&sm.p1.V[(ch) & 1][16 + ln16][kq * 8]; \
    half8 bf2 = *(const half8*)&sm.p1.V[(ch) & 1][32 + ln16][kq * 8]; \
    half8 bf3 = *(const half8*)&sm.p1.V[(ch) & 1][48 + ln16][kq * 8]; \
    acc[0][0] = __builtin_amdgcn_mfma_f32_16x16x32_f16(a0c, bf0, acc[0][0], 0, 0, 0); \
    acc[1][0] = __builtin_amdgcn_mfma_f32_16x16x32_f16(a1c, bf0, acc[1][0], 0, 0, 0); \
    acc[0][1] = __builtin_amdgcn_mfma_f32_16x16x32_f16(a0c, bf1, acc[0][1], 0, 0, 0); \
    acc[1][1] = __builtin_amdgcn_mfma_f32_16x16x32_f16(a1c, bf1, acc[1][1], 0, 0, 0); \
    acc[0][2] = __builtin_amdgcn_mfma_f32_16x16x32_f16(a0c, bf2, acc[0][2], 0, 0, 0); \
    acc[1][2] = __builtin_amdgcn_mfma_f32_16x16x32_f16(a1c, bf2, acc[1][2], 0, 0, 0); \
    acc[0][3] = __builtin_amdgcn_mfma_f32_16x16x32_f16(a0c, bf3, acc[0][3], 0, 0, 0); \
    acc[1][3] = __builtin_amdgcn_mfma_f32_16x16x32_f16(a1c, bf3, acc[1][3], 0, 0, 0); \
}

    // prefetch chunks 0,1 (register-only; before the union-transition sync)
    LOADG(0, gA0, gA1, gA2, gA3)
    LOADG(1, gB0, gB1, gB2, gB3)
    ar0 = wsrc[(size_t)(2 * wv) * 64 + lane];
    ar1 = wsrc[(size_t)(2 * wv + 1) * 64 + lane];
    __syncthreads();                       // P dead; p1 buffers live

    P1STEP(0,  gA0, gA1, gA2, gA3) P1STEP(1,  gB0, gB1, gB2, gB3)
    P1STEP(2,  gA0, gA1, gA2, gA3) P1STEP(3,  gB0, gB1, gB2, gB3)
    P1STEP(4,  gA0, gA1, gA2, gA3) P1STEP(5,  gB0, gB1, gB2, gB3)
    P1STEP(6,  gA0, gA1, gA2, gA3) P1STEP(7,  gB0, gB1, gB2, gB3)
    P1STEP(8,  gA0, gA1, gA2, gA3) P1STEP(9,  gB0, gB1, gB2, gB3)
    P1STEP(10, gA0, gA1, gA2, gA3) P1STEP(11, gB0, gB1, gB2, gB3)
    P1STEP(12, gA0, gA1, gA2, gA3) P1STEP(13, gB0, gB1, gB2, gB3)
    P1STEP(14, gA0, gA1, gA2, gA3) P1STEP(15, gB0, gB1, gB2, gB3)
    P1STEP(16, gA0, gA1, gA2, gA3) P1STEP(17, gB0, gB1, gB2, gB3)

    // epilogue: D col=lane&15 (pixel), row=(lane>>4)*4+reg (output)
#pragma unroll
    for (int mtl = 0; mtl < 2; ++mtl) {
#pragma unroll
        for (int nt = 0; nt < 4; ++nt) {
#pragma unroll
            for (int r = 0; r < 4; ++r) {
                int o  = m0 + mtl * 16 + kq * 4 + r;
                int px = nt * 16 + ln16;
                out[(size_t)(b * OUTC + o) * HW + pix0 + px] = acc[mtl][nt][r];
            }
        }
    }
}

// ---------------------------------------------------------------------------
extern "C" void kernel_launch(void* const* d_in, const int* in_sizes, int n_in,
                              void* d_out, int out_size, void* d_ws, size_t ws_size,
                              hipStream_t stream) {
    const float* x        = (const float*)d_in[0];
    const float* w_offset = (const float*)d_in[1];
    const float* b_offset = (const float*)d_in[2];
    const float* w_mask   = (const float*)d_in[3];
    const float* b_mask   = (const float*)d_in[4];
    const float* w_conv   = (const float*)d_in[5];
    float* out = (float*)d_out;

    _Float16* wpk_h = (_Float16*)d_ws;                   // 73,728 halves
    _Float16* wpk2  = wpk_h + 73728;                     // 18,432 halves
    _Float16* xtb   = wpk2 + 18432;                      // 8,388,608 halves (16.8 MB)

    prep<<<1384, 256, 0, stream>>>(x, w_conv, w_offset, w_mask, xtb, wpk_h, wpk2);
    deform_fused<<<2048, 256, 0, stream>>>(xtb, wpk_h, wpk2, b_offset, b_mask, out);
}

// Round 4
// 171.892 us; speedup vs baseline: 1.0504x; 1.0504x over previous
//
#include <hip/hip_runtime.h>
#include <math.h>

#define Himg 128
#define Wimg 128
#define HW   16384      // 128*128
#define Cin  64
#define Kk   9
#define OUTC 128
#define Bsz  8

typedef __attribute__((ext_vector_type(8))) _Float16 half8;
typedef __attribute__((ext_vector_type(4))) float   floatx4;

#define SPL8(v) ((half8){(v),(v),(v),(v),(v),(v),(v),(v)})

// ---------------------------------------------------------------------------
// fused prep kernel:
//   blocks    0..1023 : transpose+convert x[b][c][h][w] f32 -> xt[b][h][w][c] f16
//   blocks 1024..1311 : repack w_conv into MFMA-fragment order (wpk_h)
//   blocks 1312..1383 : repack w_offset/w_mask into fragment order (wpk2)
// ---------------------------------------------------------------------------
__global__ __launch_bounds__(256) void prep(const float* __restrict__ x,
                                            const float* __restrict__ w_conv,
                                            const float* __restrict__ w_offset,
                                            const float* __restrict__ w_mask,
                                            _Float16* __restrict__ xt,
                                            _Float16* __restrict__ wpk_h,
                                            _Float16* __restrict__ wpk2) {
    __shared__ _Float16 tile[Cin][130];
    int t   = threadIdx.x;
    int bid = blockIdx.x;

    if (bid < 1024) {                       // ---- transpose ----
        int b = bid >> 7;
        int h = bid & 127;
        const float* xb = x + (size_t)b * Cin * HW + (size_t)h * Wimg;
#pragma unroll
        for (int j = 0; j < 32; ++j) {
            int e = t + j * 256;            // 0..8191
            int c = e >> 7;
            int w = e & 127;
            tile[c][w] = (_Float16)xb[(size_t)c * HW + w];
        }
        __syncthreads();
        unsigned* dst = (unsigned*)xt + ((size_t)b * HW + (size_t)h * Wimg) * 32;
#pragma unroll
        for (int j = 0; j < 16; ++j) {
            int d  = t + j * 256;           // 0..4095
            int w  = d >> 5;
            int cp = d & 31;
            union { unsigned u; _Float16 hh[2]; } pk;
            pk.hh[0] = tile[2 * cp][w];
            pk.hh[1] = tile[2 * cp + 1][w];
            dst[d] = pk.u;
        }
        return;
    }

    if (bid < 1024 + 288) {                 // ---- repack main conv weights ----
        int idx = (bid - 1024) * 256 + t;   // 0 .. 73727
        if (idx < Kk * Cin * OUTC) {
            int i    = idx & 7;
            int l    = (idx >> 3) & 63;
            int g    = idx >> 9;            // 0..143
            int mt   = g & 7;
            int ch   = g >> 3;              // 0..17
            int kq   = l >> 4;
            int ln16 = l & 15;
            int o    = mt * 16 + ln16;
            int kl   = kq * 8 + i;
            int c    = (ch & 1) * 32 + kl;
            int kt   = ch >> 1;
            wpk_h[idx] = (_Float16)w_conv[(o * Cin + c) * 9 + kt];
        }
        return;
    }

    {                                       // ---- repack offset/mask weights ----
        int idx = (bid - 1312) * 256 + t;   // 0 .. 18431
        if (idx < 18 * 32 * 32) {
            int i    = idx & 7;
            int l    = (idx >> 3) & 63;
            int g    = idx >> 9;            // 0..35
            int mt0  = g & 1;
            int ch   = g >> 1;              // 0..17
            int kq   = l >> 4;
            int ln16 = l & 15;
            int m    = mt0 * 16 + ln16;
            int kl   = kq * 8 + i;
            int c    = (ch & 1) * 32 + kl;
            int kt   = ch >> 1;
            float v = 0.0f;
            if (m < 18)      v = w_offset[(m * Cin + c) * 9 + kt];
            else if (m < 27) v = w_mask[((m - 18) * Cin + c) * 9 + kt];
            wpk2[idx] = (_Float16)v;
        }
    }
}

// ---------------------------------------------------------------------------
// Fused kernel. Lane mapping for all x-side memory: q = t>>2 (pixel),
// c4 = t&3 (16B channel-quarter). Weights: direct global->VGPR fragment loads.
// Gathers: 2-deep register pipeline in explicitly named registers.
// Combine: packed-f16 (v_pk_fma_f16).
// __launch_bounds__(256,3): (256,4) capped the unified VGPR/AGPR budget and
// forced the pipeline to scratch (R2/R3: VGPR=64, +105MB HBM scratch traffic).
// ---------------------------------------------------------------------------
__global__ __launch_bounds__(256, 3) void deform_fused(
        const _Float16* __restrict__ xt, const _Float16* __restrict__ wpk_h,
        const _Float16* __restrict__ wpk2,
        const float* __restrict__ b_offset, const float* __restrict__ b_mask,
        float* __restrict__ out) {
    __shared__ union SMem {
        struct { _Float16 V0[2][64][40]; float P[32][66]; } p0;  // 18688 B
        struct { _Float16 V[2][64][40]; } p1;                    // 10240 B
    } sm;

    int t    = threadIdx.x;
    int bid  = blockIdx.x;
    int b    = bid & 7;                      // XCD-batch swizzle
    int pb   = bid >> 3;                     // 0..255
    int pix0 = pb * 64;
    int h    = pix0 >> 7;
    int w0   = pix0 & 127;                   // 0 or 64

    int lane = t & 63;
    int wv   = t >> 6;
    int q    = t >> 2;                       // pixel 0..63 (block-wide)
    int c4   = t & 3;                        // channel quarter (16B) in 32-ch half
    int kq   = lane >> 4;
    int ln16 = lane & 15;

    const _Float16* xtb  = xt + (size_t)b * HW * Cin;
    const half8* wsrc    = (const half8*)wpk_h;
    const half8* w2src   = (const half8*)wpk2;

    // ================= phase 0: offset/mask conv =================
    floatx4 acc2[2];
    acc2[0] = (floatx4){0.f, 0.f, 0.f, 0.f};
    acc2[1] = (floatx4){0.f, 0.f, 0.f, 0.f};
    int mt0 = wv & 1;                        // wave's m-tile
    int ntA = wv >> 1;                       // wave's n-tiles: ntA, ntA+2

    half8 pvA, pvB, af;

#define LOADX0(chn, DST) { \
    const int ktn = (chn) >> 1, cgn = (chn) & 1; \
    int row = h + (ktn / 3) - 1; \
    int col = w0 + q + (ktn % 3) - 1; \
    bool okc = (row >= 0) && (row < Himg) && (col >= 0) && (col < Wimg); \
    if (okc) DST = *(const half8*)(xtb + ((size_t)(row * Wimg + col)) * Cin \
                                   + cgn * 32 + c4 * 8); \
    else     DST = SPL8((_Float16)0.0f); \
}

#define P0STEP(ch, PV) { \
    *(half8*)&sm.p0.V0[(ch) & 1][q][c4 * 8] = PV; \
    half8 afc = af; \
    if ((ch) < 16) LOADX0((ch) + 2, PV); \
    if ((ch) < 17) af = w2src[((size_t)((ch) + 1) * 2 + mt0) * 64 + lane]; \
    __syncthreads(); \
    half8 b0 = *(const half8*)&sm.p0.V0[(ch) & 1][ntA * 16 + ln16][kq * 8]; \
    half8 b1 = *(const half8*)&sm.p0.V0[(ch) & 1][(ntA + 2) * 16 + ln16][kq * 8]; \
    acc2[0] = __builtin_amdgcn_mfma_f32_16x16x32_f16(afc, b0, acc2[0], 0, 0, 0); \
    acc2[1] = __builtin_amdgcn_mfma_f32_16x16x32_f16(afc, b1, acc2[1], 0, 0, 0); \
}

    LOADX0(0, pvA)
    LOADX0(1, pvB)
    af = w2src[(size_t)mt0 * 64 + lane];

    P0STEP(0,  pvA) P0STEP(1,  pvB) P0STEP(2,  pvA) P0STEP(3,  pvB)
    P0STEP(4,  pvA) P0STEP(5,  pvB) P0STEP(6,  pvA) P0STEP(7,  pvB)
    P0STEP(8,  pvA) P0STEP(9,  pvB) P0STEP(10, pvA) P0STEP(11, pvB)
    P0STEP(12, pvA) P0STEP(13, pvB) P0STEP(14, pvA) P0STEP(15, pvB)
    P0STEP(16, pvA) P0STEP(17, pvB)

    // write P (27 used rows x 64 px, fp32) — P disjoint from V0, no race
#pragma unroll
    for (int j = 0; j < 2; ++j) {
        int nt = ntA + 2 * j;
#pragma unroll
        for (int r = 0; r < 4; ++r)
            sm.p0.P[mt0 * 16 + kq * 4 + r][nt * 16 + ln16] = acc2[j][r];
    }
    __syncthreads();

    // ---- per-pixel geometry (pixel q) -> registers ----
    // geomr[k] = o00 | dx1<<14 | dy1<<15  (cell index + corner-step flags)
    int      geomr[9];
    unsigned wab[9], wcd[9];                 // f16-packed (w00,w01),(w10,w11)
    {
        float fh = (float)h, fw = (float)(w0 + q);
#pragma unroll
        for (int k = 0; k < 9; ++k) {
            float dyv = sm.p0.P[2 * k][q]     + b_offset[2 * k];
            float dxv = sm.p0.P[2 * k + 1][q] + b_offset[2 * k + 1];
            float mz  = sm.p0.P[18 + k][q]    + b_mask[k];
            float mkv = 1.0f / (1.0f + expf(-mz));

            float gy  = fh + (float)(k / 3) - 1.0f + dyv;
            float gx  = fw + (float)(k % 3) - 1.0f + dxv;
            float y0f = floorf(gy), x0f = floorf(gx);
            int   y0  = (int)y0f,   x0 = (int)x0f;
            float wy  = gy - y0f,   wx = gx - x0f;
            int   y1  = y0 + 1,     x1 = x0 + 1;

            bool vy0 = (y0 >= 0) && (y0 < Himg);
            bool vy1 = (y1 >= 0) && (y1 < Himg);
            bool vx0 = (x0 >= 0) && (x0 < Wimg);
            bool vx1 = (x1 >= 0) && (x1 < Wimg);

            float w00 = (vy0 && vx0) ? (1.0f - wy) * (1.0f - wx) * mkv : 0.0f;
            float w01 = (vy0 && vx1) ? (1.0f - wy) * wx          * mkv : 0.0f;
            float w10 = (vy1 && vx0) ? wy          * (1.0f - wx) * mkv : 0.0f;
            float w11 = (vy1 && vx1) ? wy          * wx          * mkv : 0.0f;

            int y0c = min(max(y0, 0), Himg - 1), y1c = min(max(y1, 0), Himg - 1);
            int x0c = min(max(x0, 0), Wimg - 1), x1c = min(max(x1, 0), Wimg - 1);
            geomr[k] = (y0c * Wimg + x0c) | ((x1c - x0c) << 14) | ((y1c - y0c) << 15);
            union { unsigned u; _Float16 hh[2]; } pk;
            pk.hh[0] = (_Float16)w00; pk.hh[1] = (_Float16)w01; wab[k] = pk.u;
            pk.hh[0] = (_Float16)w10; pk.hh[1] = (_Float16)w11; wcd[k] = pk.u;
        }
    }

    // ================= phase 1: deformable sampling + GEMM =================
    floatx4 acc[2][4];
#pragma unroll
    for (int i = 0; i < 2; ++i)
#pragma unroll
        for (int j = 0; j < 4; ++j) acc[i][j] = (floatx4){0.f, 0.f, 0.f, 0.f};
    int m0 = wv * 32;

    half8 gA0, gA1, gA2, gA3, gB0, gB1, gB2, gB3, ar0, ar1;

#define LOADG(chn, D0, D1, D2, D3) { \
    int gg = geomr[(chn) >> 1]; \
    const _Float16* xc = xtb + (size_t)(gg & 0x3fff) * Cin \
                         + ((chn) & 1) * 32 + c4 * 8; \
    int ob = (gg & 0x4000) >> 8;   /* dx1*64   */ \
    int oc = (gg & 0x8000) >> 2;   /* dy1*8192 */ \
    D0 = *(const half8*)(xc); \
    D1 = *(const half8*)(xc + ob); \
    D2 = *(const half8*)(xc + oc); \
    D3 = *(const half8*)(xc + oc + ob); \
}

#define P1STEP(ch, G0, G1, G2, G3) { \
    union { unsigned u; _Float16 hh[2]; } u1, u2; \
    u1.u = wab[(ch) >> 1];  u2.u = wcd[(ch) >> 1]; \
    half8 vv = G0 * SPL8(u1.hh[0]) + G1 * SPL8(u1.hh[1]) \
             + G2 * SPL8(u2.hh[0]) + G3 * SPL8(u2.hh[1]); \
    *(half8*)&sm.p1.V[(ch) & 1][q][c4 * 8] = vv; \
    half8 a0c = ar0, a1c = ar1; \
    if ((ch) < 16) LOADG((ch) + 2, G0, G1, G2, G3); \
    if ((ch) < 17) { \
        ar0 = wsrc[((size_t)((ch) + 1) * 8 + 2 * wv) * 64 + lane]; \
        ar1 = wsrc[((size_t)((ch) + 1) * 8 + 2 * wv + 1) * 64 + lane]; \
    } \
    __syncthreads(); \
    half8 bf0 = *(const half8*)&sm.p1.V[(ch) & 1][ 0 + ln16][kq * 8]; \
    half8 bf1 = *(const half8*)&sm.p1.V[(ch) & 1][16 + ln16][kq * 8]; \
    half8 bf2 = *(const half8*)&sm.p1.V[(ch) & 1][32 + ln16][kq * 8]; \
    half8 bf3 = *(const half8*)&sm.p1.V[(ch) & 1][48 + ln16][kq * 8]; \
    acc[0][0] = __builtin_amdgcn_mfma_f32_16x16x32_f16(a0c, bf0, acc[0][0], 0, 0, 0); \
    acc[1][0] = __builtin_amdgcn_mfma_f32_16x16x32_f16(a1c, bf0, acc[1][0], 0, 0, 0); \
    acc[0][1] = __builtin_amdgcn_mfma_f32_16x16x32_f16(a0c, bf1, acc[0][1], 0, 0, 0); \
    acc[1][1] = __builtin_amdgcn_mfma_f32_16x16x32_f16(a1c, bf1, acc[1][1], 0, 0, 0); \
    acc[0][2] = __builtin_amdgcn_mfma_f32_16x16x32_f16(a0c, bf2, acc[0][2], 0, 0, 0); \
    acc[1][2] = __builtin_amdgcn_mfma_f32_16x16x32_f16(a1c, bf2, acc[1][2], 0, 0, 0); \
    acc[0][3] = __builtin_amdgcn_mfma_f32_16x16x32_f16(a0c, bf3, acc[0][3], 0, 0, 0); \
    acc[1][3] = __builtin_amdgcn_mfma_f32_16x16x32_f16(a1c, bf3, acc[1][3], 0, 0, 0); \
}

    // prefetch chunks 0,1 (register-only; before the union-transition sync)
    LOADG(0, gA0, gA1, gA2, gA3)
    LOADG(1, gB0, gB1, gB2, gB3)
    ar0 = wsrc[(size_t)(2 * wv) * 64 + lane];
    ar1 = wsrc[(size_t)(2 * wv + 1) * 64 + lane];
    __syncthreads();                       // P dead; p1 buffers live

    P1STEP(0,  gA0, gA1, gA2, gA3) P1STEP(1,  gB0, gB1, gB2, gB3)
    P1STEP(2,  gA0, gA1, gA2, gA3) P1STEP(3,  gB0, gB1, gB2, gB3)
    P1STEP(4,  gA0, gA1, gA2, gA3) P1STEP(5,  gB0, gB1, gB2, gB3)
    P1STEP(6,  gA0, gA1, gA2, gA3) P1STEP(7,  gB0, gB1, gB2, gB3)
    P1STEP(8,  gA0, gA1, gA2, gA3) P1STEP(9,  gB0, gB1, gB2, gB3)
    P1STEP(10, gA0, gA1, gA2, gA3) P1STEP(11, gB0, gB1, gB2, gB3)
    P1STEP(12, gA0, gA1, gA2, gA3) P1STEP(13, gB0, gB1, gB2, gB3)
    P1STEP(14, gA0, gA1, gA2, gA3) P1STEP(15, gB0, gB1, gB2, gB3)
    P1STEP(16, gA0, gA1, gA2, gA3) P1STEP(17, gB0, gB1, gB2, gB3)

    // epilogue: D col=lane&15 (pixel), row=(lane>>4)*4+reg (output)
#pragma unroll
    for (int mtl = 0; mtl < 2; ++mtl) {
#pragma unroll
        for (int nt = 0; nt < 4; ++nt) {
#pragma unroll
            for (int r = 0; r < 4; ++r) {
                int o  = m0 + mtl * 16 + kq * 4 + r;
                int px = nt * 16 + ln16;
                out[(size_t)(b * OUTC + o) * HW + pix0 + px] = acc[mtl][nt][r];
            }
        }
    }
}

// ---------------------------------------------------------------------------
extern "C" void kernel_launch(void* const* d_in, const int* in_sizes, int n_in,
                              void* d_out, int out_size, void* d_ws, size_t ws_size,
                              hipStream_t stream) {
    const float* x        = (const float*)d_in[0];
    const float* w_offset = (const float*)d_in[1];
    const float* b_offset = (const float*)d_in[2];
    const float* w_mask   = (const float*)d_in[3];
    const float* b_mask   = (const float*)d_in[4];
    const float* w_conv   = (const float*)d_in[5];
    float* out = (float*)d_out;

    _Float16* wpk_h = (_Float16*)d_ws;                   // 73,728 halves
    _Float16* wpk2  = wpk_h + 73728;                     // 18,432 halves
    _Float16* xtb   = wpk2 + 18432;                      // 8,388,608 halves (16.8 MB)

    prep<<<1384, 256, 0, stream>>>(x, w_conv, w_offset, w_mask, xtb, wpk_h, wpk2);
    deform_fused<<<2048, 256, 0, stream>>>(xtb, wpk_h, wpk2, b_offset, b_mask, out);
}

// Round 5
// 165.224 us; speedup vs baseline: 1.0928x; 1.0404x over previous
//
#include <hip/hip_runtime.h>
#include <math.h>

#define Himg 128
#define Wimg 128
#define HW   16384      // 128*128
#define Cin  64
#define Kk   9
#define OUTC 128
#define Bsz  8

typedef __attribute__((ext_vector_type(8))) _Float16 half8;
typedef __attribute__((ext_vector_type(4))) float   floatx4;

#define SPL8(v) ((half8){(v),(v),(v),(v),(v),(v),(v),(v)})

// ---------------------------------------------------------------------------
// fused prep kernel:
//   blocks    0..1023 : transpose+convert x[b][c][h][w] f32 -> xt[b][h][w][c] f16
//   blocks 1024..1311 : repack w_conv into MFMA-fragment order (wpk_h)
//   blocks 1312..1383 : repack w_offset/w_mask into fragment order (wpk2)
// ---------------------------------------------------------------------------
__global__ __launch_bounds__(256) void prep(const float* __restrict__ x,
                                            const float* __restrict__ w_conv,
                                            const float* __restrict__ w_offset,
                                            const float* __restrict__ w_mask,
                                            _Float16* __restrict__ xt,
                                            _Float16* __restrict__ wpk_h,
                                            _Float16* __restrict__ wpk2) {
    __shared__ _Float16 tile[Cin][130];
    int t   = threadIdx.x;
    int bid = blockIdx.x;

    if (bid < 1024) {                       // ---- transpose ----
        int b = bid >> 7;
        int h = bid & 127;
        const float* xb = x + (size_t)b * Cin * HW + (size_t)h * Wimg;
#pragma unroll
        for (int j = 0; j < 32; ++j) {
            int e = t + j * 256;            // 0..8191
            int c = e >> 7;
            int w = e & 127;
            tile[c][w] = (_Float16)xb[(size_t)c * HW + w];
        }
        __syncthreads();
        unsigned* dst = (unsigned*)xt + ((size_t)b * HW + (size_t)h * Wimg) * 32;
#pragma unroll
        for (int j = 0; j < 16; ++j) {
            int d  = t + j * 256;           // 0..4095
            int w  = d >> 5;
            int cp = d & 31;
            union { unsigned u; _Float16 hh[2]; } pk;
            pk.hh[0] = tile[2 * cp][w];
            pk.hh[1] = tile[2 * cp + 1][w];
            dst[d] = pk.u;
        }
        return;
    }

    if (bid < 1024 + 288) {                 // ---- repack main conv weights ----
        int idx = (bid - 1024) * 256 + t;   // 0 .. 73727
        if (idx < Kk * Cin * OUTC) {
            int i    = idx & 7;
            int l    = (idx >> 3) & 63;
            int g    = idx >> 9;            // 0..143
            int mt   = g & 7;
            int ch   = g >> 3;              // 0..17
            int kq   = l >> 4;
            int ln16 = l & 15;
            int o    = mt * 16 + ln16;
            int kl   = kq * 8 + i;
            int c    = (ch & 1) * 32 + kl;
            int kt   = ch >> 1;
            wpk_h[idx] = (_Float16)w_conv[(o * Cin + c) * 9 + kt];
        }
        return;
    }

    {                                       // ---- repack offset/mask weights ----
        int idx = (bid - 1312) * 256 + t;   // 0 .. 18431
        if (idx < 18 * 32 * 32) {
            int i    = idx & 7;
            int l    = (idx >> 3) & 63;
            int g    = idx >> 9;            // 0..35
            int mt0  = g & 1;
            int ch   = g >> 1;              // 0..17
            int kq   = l >> 4;
            int ln16 = l & 15;
            int m    = mt0 * 16 + ln16;
            int kl   = kq * 8 + i;
            int c    = (ch & 1) * 32 + kl;
            int kt   = ch >> 1;
            float v = 0.0f;
            if (m < 18)      v = w_offset[(m * Cin + c) * 9 + kt];
            else if (m < 27) v = w_mask[((m - 18) * Cin + c) * 9 + kt];
            wpk2[idx] = (_Float16)v;
        }
    }
}

// ---------------------------------------------------------------------------
// Fused kernel, BARRIER-FREE per-wave decomposition.
// Wave w owns ALL 128 outputs for pixels [pix0 + w*16, pix0 + w*16 + 16).
// Its own lanes produce exactly the V data it consumes (q = wv*16 + (lane>>2),
// c4 = lane&3), so V tiles and conv results P are PER-WAVE PRIVATE LDS:
// 1 b128 write + 1 b128 read per wave per chunk, no __syncthreads anywhere.
// Weights stream as per-lane MFMA fragments from global (L1/L2-hot, issued a
// full combine-phase ahead of the MFMAs). Gathers: 2-deep register pipeline.
// __launch_bounds__(256,3): (256,4) caps unified VGPR budget -> scratch (R2/R3).
// ---------------------------------------------------------------------------
__global__ __launch_bounds__(256, 3) void deform_fused(
        const _Float16* __restrict__ xt, const _Float16* __restrict__ wpk_h,
        const _Float16* __restrict__ wpk2,
        const float* __restrict__ b_offset, const float* __restrict__ b_mask,
        float* __restrict__ out) {
    __shared__ _Float16 Vw[4][2][16][40];   // per-wave double-buffered V: 10240 B
    __shared__ float    Pw[4][32][16];      // per-wave conv outputs:       8192 B

    int t    = threadIdx.x;
    int bid  = blockIdx.x;
    int b    = bid & 7;                      // XCD-batch swizzle
    int pb   = bid >> 3;                     // 0..255
    int pix0 = pb * 64;
    int h    = pix0 >> 7;
    int w0   = pix0 & 127;                   // 0 or 64

    int lane = t & 63;
    int wv   = t >> 6;
    int q    = t >> 2;                       // pixel in slab = wv*16 + (lane>>2)
    int qloc = (lane >> 2) & 15;             // pixel within wave
    int c4   = t & 3;                        // 16B channel-quarter in 32-ch half
    int kq   = lane >> 4;
    int ln16 = lane & 15;

    const _Float16* xtb  = xt + (size_t)b * HW * Cin;
    const half8* wsrc    = (const half8*)wpk_h;
    const half8* w2src   = (const half8*)wpk2;

    // ================= phase 0: offset/mask conv (per-wave) =================
    floatx4 acc2_0 = (floatx4){0.f, 0.f, 0.f, 0.f};
    floatx4 acc2_1 = (floatx4){0.f, 0.f, 0.f, 0.f};

    half8 pvA, pvB;

#define LOADX0(chn, DST) { \
    const int ktn = (chn) >> 1, cgn = (chn) & 1; \
    int row = h + (ktn / 3) - 1; \
    int col = w0 + q + (ktn % 3) - 1; \
    bool okc = (row >= 0) && (row < Himg) && (col >= 0) && (col < Wimg); \
    if (okc) DST = *(const half8*)(xtb + ((size_t)(row * Wimg + col)) * Cin \
                                   + cgn * 32 + c4 * 8); \
    else     DST = SPL8((_Float16)0.0f); \
}

#define P0STEP(ch, PV) { \
    half8 af0 = w2src[((size_t)(ch) * 2 + 0) * 64 + lane]; \
    half8 af1 = w2src[((size_t)(ch) * 2 + 1) * 64 + lane]; \
    *(half8*)&Vw[wv][(ch) & 1][qloc][c4 * 8] = PV; \
    if ((ch) < 16) LOADX0((ch) + 2, PV); \
    half8 bf = *(const half8*)&Vw[wv][(ch) & 1][ln16][kq * 8]; \
    acc2_0 = __builtin_amdgcn_mfma_f32_16x16x32_f16(af0, bf, acc2_0, 0, 0, 0); \
    acc2_1 = __builtin_amdgcn_mfma_f32_16x16x32_f16(af1, bf, acc2_1, 0, 0, 0); \
}

    LOADX0(0, pvA)
    LOADX0(1, pvB)

    P0STEP(0,  pvA) P0STEP(1,  pvB) P0STEP(2,  pvA) P0STEP(3,  pvB)
    P0STEP(4,  pvA) P0STEP(5,  pvB) P0STEP(6,  pvA) P0STEP(7,  pvB)
    P0STEP(8,  pvA) P0STEP(9,  pvB) P0STEP(10, pvA) P0STEP(11, pvB)
    P0STEP(12, pvA) P0STEP(13, pvB) P0STEP(14, pvA) P0STEP(15, pvB)
    P0STEP(16, pvA) P0STEP(17, pvB)

    // conv results -> per-wave P (row m = output chan, col = local pixel)
#pragma unroll
    for (int r = 0; r < 4; ++r) {
        Pw[wv][kq * 4 + r][ln16]      = acc2_0[r];
        Pw[wv][16 + kq * 4 + r][ln16] = acc2_1[r];
    }

    // ---- per-pixel geometry (pixel q, per-wave P read; no barrier) ----
    // geomr[k] = o00 | dx1<<14 | dy1<<15  (cell index + corner-step flags)
    int      geomr[9];
    unsigned wab[9], wcd[9];                 // f16-packed (w00,w01),(w10,w11)
    {
        float fh = (float)h, fw = (float)(w0 + q);
#pragma unroll
        for (int k = 0; k < 9; ++k) {
            float dyv = Pw[wv][2 * k][qloc]     + b_offset[2 * k];
            float dxv = Pw[wv][2 * k + 1][qloc] + b_offset[2 * k + 1];
            float mz  = Pw[wv][18 + k][qloc]    + b_mask[k];
            float mkv = 1.0f / (1.0f + expf(-mz));

            float gy  = fh + (float)(k / 3) - 1.0f + dyv;
            float gx  = fw + (float)(k % 3) - 1.0f + dxv;
            float y0f = floorf(gy), x0f = floorf(gx);
            int   y0  = (int)y0f,   x0 = (int)x0f;
            float wy  = gy - y0f,   wx = gx - x0f;
            int   y1  = y0 + 1,     x1 = x0 + 1;

            bool vy0 = (y0 >= 0) && (y0 < Himg);
            bool vy1 = (y1 >= 0) && (y1 < Himg);
            bool vx0 = (x0 >= 0) && (x0 < Wimg);
            bool vx1 = (x1 >= 0) && (x1 < Wimg);

            float w00 = (vy0 && vx0) ? (1.0f - wy) * (1.0f - wx) * mkv : 0.0f;
            float w01 = (vy0 && vx1) ? (1.0f - wy) * wx          * mkv : 0.0f;
            float w10 = (vy1 && vx0) ? wy          * (1.0f - wx) * mkv : 0.0f;
            float w11 = (vy1 && vx1) ? wy          * wx          * mkv : 0.0f;

            int y0c = min(max(y0, 0), Himg - 1), y1c = min(max(y1, 0), Himg - 1);
            int x0c = min(max(x0, 0), Wimg - 1), x1c = min(max(x1, 0), Wimg - 1);
            geomr[k] = (y0c * Wimg + x0c) | ((x1c - x0c) << 14) | ((y1c - y0c) << 15);
            union { unsigned u; _Float16 hh[2]; } pk;
            pk.hh[0] = (_Float16)w00; pk.hh[1] = (_Float16)w01; wab[k] = pk.u;
            pk.hh[0] = (_Float16)w10; pk.hh[1] = (_Float16)w11; wcd[k] = pk.u;
        }
    }

    // ================= phase 1: sampling + GEMM (per-wave) =================
    floatx4 acc[8];
#pragma unroll
    for (int i = 0; i < 8; ++i) acc[i] = (floatx4){0.f, 0.f, 0.f, 0.f};

    half8 gA0, gA1, gA2, gA3, gB0, gB1, gB2, gB3;

#define LOADG(chn, D0, D1, D2, D3) { \
    int gg = geomr[(chn) >> 1]; \
    const _Float16* xc = xtb + (size_t)(gg & 0x3fff) * Cin \
                         + ((chn) & 1) * 32 + c4 * 8; \
    int ob = (gg & 0x4000) >> 8;   /* dx1*64   */ \
    int oc = (gg & 0x8000) >> 2;   /* dy1*8192 */ \
    D0 = *(const half8*)(xc); \
    D1 = *(const half8*)(xc + ob); \
    D2 = *(const half8*)(xc + oc); \
    D3 = *(const half8*)(xc + oc + ob); \
}

#define P1STEP(ch, G0, G1, G2, G3) { \
    /* this-chunk A-fragments: issue first, consume after combine+LDS */ \
    half8 ar0 = wsrc[((size_t)(ch) * 8 + 0) * 64 + lane]; \
    half8 ar1 = wsrc[((size_t)(ch) * 8 + 1) * 64 + lane]; \
    half8 ar2 = wsrc[((size_t)(ch) * 8 + 2) * 64 + lane]; \
    half8 ar3 = wsrc[((size_t)(ch) * 8 + 3) * 64 + lane]; \
    half8 ar4 = wsrc[((size_t)(ch) * 8 + 4) * 64 + lane]; \
    half8 ar5 = wsrc[((size_t)(ch) * 8 + 5) * 64 + lane]; \
    half8 ar6 = wsrc[((size_t)(ch) * 8 + 6) * 64 + lane]; \
    half8 ar7 = wsrc[((size_t)(ch) * 8 + 7) * 64 + lane]; \
    union { unsigned u; _Float16 hh[2]; } u1, u2; \
    u1.u = wab[(ch) >> 1];  u2.u = wcd[(ch) >> 1]; \
    half8 vv = G0 * SPL8(u1.hh[0]) + G1 * SPL8(u1.hh[1]) \
             + G2 * SPL8(u2.hh[0]) + G3 * SPL8(u2.hh[1]); \
    *(half8*)&Vw[wv][(ch) & 1][qloc][c4 * 8] = vv; \
    if ((ch) < 16) LOADG((ch) + 2, G0, G1, G2, G3); \
    half8 bf = *(const half8*)&Vw[wv][(ch) & 1][ln16][kq * 8]; \
    acc[0] = __builtin_amdgcn_mfma_f32_16x16x32_f16(ar0, bf, acc[0], 0, 0, 0); \
    acc[1] = __builtin_amdgcn_mfma_f32_16x16x32_f16(ar1, bf, acc[1], 0, 0, 0); \
    acc[2] = __builtin_amdgcn_mfma_f32_16x16x32_f16(ar2, bf, acc[2], 0, 0, 0); \
    acc[3] = __builtin_amdgcn_mfma_f32_16x16x32_f16(ar3, bf, acc[3], 0, 0, 0); \
    acc[4] = __builtin_amdgcn_mfma_f32_16x16x32_f16(ar4, bf, acc[4], 0, 0, 0); \
    acc[5] = __builtin_amdgcn_mfma_f32_16x16x32_f16(ar5, bf, acc[5], 0, 0, 0); \
    acc[6] = __builtin_amdgcn_mfma_f32_16x16x32_f16(ar6, bf, acc[6], 0, 0, 0); \
    acc[7] = __builtin_amdgcn_mfma_f32_16x16x32_f16(ar7, bf, acc[7], 0, 0, 0); \
}

    // prefetch gather chunks 0,1 (register-only)
    LOADG(0, gA0, gA1, gA2, gA3)
    LOADG(1, gB0, gB1, gB2, gB3)

    P1STEP(0,  gA0, gA1, gA2, gA3) P1STEP(1,  gB0, gB1, gB2, gB3)
    P1STEP(2,  gA0, gA1, gA2, gA3) P1STEP(3,  gB0, gB1, gB2, gB3)
    P1STEP(4,  gA0, gA1, gA2, gA3) P1STEP(5,  gB0, gB1, gB2, gB3)
    P1STEP(6,  gA0, gA1, gA2, gA3) P1STEP(7,  gB0, gB1, gB2, gB3)
    P1STEP(8,  gA0, gA1, gA2, gA3) P1STEP(9,  gB0, gB1, gB2, gB3)
    P1STEP(10, gA0, gA1, gA2, gA3) P1STEP(11, gB0, gB1, gB2, gB3)
    P1STEP(12, gA0, gA1, gA2, gA3) P1STEP(13, gB0, gB1, gB2, gB3)
    P1STEP(14, gA0, gA1, gA2, gA3) P1STEP(15, gB0, gB1, gB2, gB3)
    P1STEP(16, gA0, gA1, gA2, gA3) P1STEP(17, gB0, gB1, gB2, gB3)

    // epilogue: D col=ln16 (local pixel), row=(kq*4+r) within m-tile mt
#pragma unroll
    for (int mt = 0; mt < 8; ++mt) {
#pragma unroll
        for (int r = 0; r < 4; ++r) {
            int o = mt * 16 + kq * 4 + r;
            out[(size_t)(b * OUTC + o) * HW + pix0 + wv * 16 + ln16] = acc[mt][r];
        }
    }
}

// ---------------------------------------------------------------------------
extern "C" void kernel_launch(void* const* d_in, const int* in_sizes, int n_in,
                              void* d_out, int out_size, void* d_ws, size_t ws_size,
                              hipStream_t stream) {
    const float* x        = (const float*)d_in[0];
    const float* w_offset = (const float*)d_in[1];
    const float* b_offset = (const float*)d_in[2];
    const float* w_mask   = (const float*)d_in[3];
    const float* b_mask   = (const float*)d_in[4];
    const float* w_conv   = (const float*)d_in[5];
    float* out = (float*)d_out;

    _Float16* wpk_h = (_Float16*)d_ws;                   // 73,728 halves
    _Float16* wpk2  = wpk_h + 73728;                     // 18,432 halves
    _Float16* xtb   = wpk2 + 18432;                      // 8,388,608 halves (16.8 MB)

    prep<<<1384, 256, 0, stream>>>(x, w_conv, w_offset, w_mask, xtb, wpk_h, wpk2);
    deform_fused<<<2048, 256, 0, stream>>>(xtb, wpk_h, wpk2, b_offset, b_mask, out);
}